// Round 8
// baseline (54.920 us; speedup 1.0000x reference)
//
#include <hip/hip_runtime.h>
#include <stdint.h>

typedef short short8 __attribute__((ext_vector_type(8)));
typedef float f32x4 __attribute__((ext_vector_type(4)));
typedef float f32x2 __attribute__((ext_vector_type(2)));

#define B_ 2048
#define I_ 16
#define M_ 4
#define R_ 4096
#define C_ 10
#define NX 17           // I+1
#define NW 170          // NX*C
#define NPAD 192        // 12 MFMA n-tiles
#define KSPLIT 32
#define KCH (R_ / KSPLIT)   // 128
#define NIT (KCH / 32)      // 4

// d_out layout: y_hat (B_*C_) | norm_fs (B_*R_) | x_ext (B_*NX)
#define Y_OFF    0
#define NORM_OFF (B_ * C_)
#define XE_OFF   (B_ * C_ + B_ * R_)

// d_ws layout (bytes)
#define PK_OFF    0                                   // packed rule idx, 16 KB
#define WT_OFF    16384                               // Wt bf16 [NPAD][R_], 1.57 MB

#define MFMA16(a, b, c) __builtin_amdgcn_mfma_f32_16x16x32_bf16(a, b, c, 0, 0, 0)

__device__ __forceinline__ uint16_t f2bf(float f) {
    uint32_t u = __builtin_bit_cast(uint32_t, f);
    uint32_t r = u + 0x7fffu + ((u >> 16) & 1u);    // RNE
    return (uint16_t)(r >> 16);
}

// ---------------- pack rule_idx + zero y_hat region --------------------------
__global__ __launch_bounds__(256) void pack_kernel(
        const int* __restrict__ rule_idx, uint32_t* __restrict__ packed,
        float* __restrict__ out) {
    int t = threadIdx.x;
    int r = blockIdx.x * 256 + t;               // grid = 16 blocks
    uint32_t p = 0;
#pragma unroll
    for (int i = 0; i < I_; ++i)
        p |= ((uint32_t)rule_idx[i * R_ + r] & 3u) << (2 * i);
    packed[r] = p;
    // zero y: B_*C_ = 81920 floats = 20480 float4, 4096 threads * 5 each
    f32x4* y4 = (f32x4*)(out + Y_OFF);
    int base = (blockIdx.x * 256 + t) * 5;
#pragma unroll
    for (int u = 0; u < 5; ++u) y4[base + u] = (f32x4){0.f, 0.f, 0.f, 0.f};
}

// ---------------- fuzz (blocks 0..2047) + wt transpose (blocks 2048..2111) ---
__global__ __launch_bounds__(256) void fuzz_wt_kernel(
        const float* __restrict__ x, const float* __restrict__ centers,
        const float* __restrict__ widths, const uint32_t* __restrict__ packed,
        const float* __restrict__ cons, float* __restrict__ out,
        uint16_t* __restrict__ nfb, uint16_t* __restrict__ wt) {
    __shared__ float smem[16 * (NW + 2)];       // 11 KB, shared by both paths
    int t = threadIdx.x;

    if (blockIdx.x >= B_) {
        // ---- transpose 64 k-rows of consequents into wt[n][k] bf16 ----
        int k0 = (blockIdx.x - B_) * 64;
        float (*lt)[NW + 2] = (float (*)[NW + 2])smem;
#pragma unroll
        for (int tile = 0; tile < 4; ++tile) {
            int kt0 = k0 + tile * 16;
            for (int idx = t; idx < 16 * NW; idx += 256) {
                int k = idx / NW, n = idx - k * NW;
                lt[k][n] = cons[(size_t)(kt0 + k) * NW + n];
            }
            __syncthreads();
            for (int idx = t; idx < NPAD * 8; idx += 256) {
                int n = idx >> 3, kp = idx & 7;
                uint32_t v = 0;
                if (n < NW) {
                    uint32_t v0 = f2bf(lt[kp * 2][n]);
                    uint32_t v1 = f2bf(lt[kp * 2 + 1][n]);
                    v = v0 | (v1 << 16);
                }
                *(uint32_t*)(wt + (size_t)n * R_ + kt0 + kp * 2) = v;
            }
            __syncthreads();
        }
        return;
    }

    // ---- fuzz path: r6 logic, smem aliased ----
    int b = blockIdx.x;
    float* xs   = smem;             // [16]
    float* zl   = smem + 16;        // [64]
    float* tab4 = smem + 80;        // [1024]
    float* wsum = smem + 1104;      // [4]

    if (t < I_) xs[t] = x[b * I_ + t];
    if (t < NX) out[XE_OFF + b * NX + t] = (t < I_) ? x[b * I_ + t] : 1.0f;
    __syncthreads();

    if (t < 64) {
        int i = t >> 2, m = t & 3;
        float d = xs[i] - centers[i * M_ + m];
        float w = widths[i * M_ + m];
        zl[t] = -(d * d) / (2.0f * w * w) + 1e-9f;
    }
    __syncthreads();

#pragma unroll
    for (int u = 0; u < 4; ++u) {
        int idx = t + u * 256;
        int q = idx >> 8, xq = idx & 255;
        tab4[idx] = zl[q * 16 +      (xq & 3)]
                  + zl[q * 16 +  4 + ((xq >> 2) & 3)]
                  + zl[q * 16 +  8 + ((xq >> 4) & 3)]
                  + zl[q * 16 + 12 + ((xq >> 6) & 3)];
    }
    __syncthreads();

    uint2 pk[8];
#pragma unroll
    for (int k = 0; k < 8; ++k)
        pk[k] = *(const uint2*)(packed + t * 2 + k * 512);

    float fs[16];
    float lsum = 0.f;
#pragma unroll
    for (int k = 0; k < 8; ++k) {
#pragma unroll
        for (int j = 0; j < 2; ++j) {
            uint32_t p = j ? pk[k].y : pk[k].x;
            float s = tab4[        p         & 255]
                    + tab4[256 + ((p >>  8) & 255)]
                    + tab4[512 + ((p >> 16) & 255)]
                    + tab4[768 + ((p >> 24) & 255)];
            float f = __expf(s);
            fs[k * 2 + j] = f;
            lsum += f;
        }
    }
#pragma unroll
    for (int off = 32; off > 0; off >>= 1) lsum += __shfl_down(lsum, off);
    if ((t & 63) == 0) wsum[t >> 6] = lsum;
    __syncthreads();
    float inv = 1.0f / (wsum[0] + wsum[1] + wsum[2] + wsum[3] + 1e-9f);

    float* orow = out + NORM_OFF + (size_t)b * R_ + t * 2;
    uint16_t* nrow = nfb + (size_t)b * R_ + t * 2;
#pragma unroll
    for (int k = 0; k < 8; ++k) {
        float n0 = fs[k * 2] * inv;
        float n1 = fs[k * 2 + 1] * inv;
        f32x2 o2 = {n0, n1};
        __builtin_nontemporal_store(o2, (f32x2*)(orow + k * 512));
        uint32_t pkd = (uint32_t)f2bf(n0) | ((uint32_t)f2bf(n1) << 16);
        *(uint32_t*)(nrow + k * 512) = pkd;
    }
}

// ---------------- MFMA GEMM + fused x_ext contraction + atomic y ------------
__global__ __launch_bounds__(256, 3) void gemm_kernel(
        const uint16_t* __restrict__ nfb,   // [B_][R_] bf16
        const uint16_t* __restrict__ wt,    // [NPAD][R_] bf16 (= W^T padded)
        const float* __restrict__ xe,       // [B_][NX]
        float* __restrict__ out) {          // y accumulated atomically
    int bt  = blockIdx.x;           // 0..31
    int ks  = blockIdx.y;           // 0..KSPLIT-1
    int tid = threadIdx.x;
    int wid = tid >> 6;
    int lane = tid & 63;
    int b0 = bt * 64;
    int k0 = ks * KCH;
    int row = lane & 15;
    int kf  = (lane >> 4) * 8;

    f32x4 acc[4][3];
#pragma unroll
    for (int mt = 0; mt < 4; ++mt)
#pragma unroll
        for (int nt = 0; nt < 3; ++nt) acc[mt][nt] = (f32x4){0.f, 0.f, 0.f, 0.f};

    const uint16_t* Ab = nfb + (size_t)(b0 + row) * R_ + k0 + kf;
    const uint16_t* Bb = wt  + (size_t)(wid * 48 + row) * R_ + k0 + kf;

    short8 a[2][4], w[2][3];
#define LOADS(buf, kk)                                                   \
    do {                                                                 \
        a[buf][0] = *(const short8*)(Ab + (kk));                         \
        a[buf][1] = *(const short8*)(Ab + (size_t)16 * R_ + (kk));       \
        a[buf][2] = *(const short8*)(Ab + (size_t)32 * R_ + (kk));       \
        a[buf][3] = *(const short8*)(Ab + (size_t)48 * R_ + (kk));       \
        w[buf][0] = *(const short8*)(Bb + (kk));                         \
        w[buf][1] = *(const short8*)(Bb + (size_t)16 * R_ + (kk));       \
        w[buf][2] = *(const short8*)(Bb + (size_t)32 * R_ + (kk));       \
    } while (0)

    LOADS(0, 0);
#pragma unroll
    for (int it = 0; it < NIT; ++it) {
        int cur = it & 1;
        if (it + 1 < NIT) LOADS(cur ^ 1, (it + 1) * 32);
#pragma unroll
        for (int nt = 0; nt < 3; ++nt)
#pragma unroll
            for (int mt = 0; mt < 4; ++mt)
                acc[mt][nt] = MFMA16(a[cur][mt], w[cur][nt], acc[mt][nt]);
    }
#undef LOADS

    // C/D layout: col = lane&15, row = (lane>>4)*4 + j
    __shared__ float tile[64][NPAD];
#pragma unroll
    for (int mt = 0; mt < 4; ++mt)
#pragma unroll
        for (int nt = 0; nt < 3; ++nt)
#pragma unroll
            for (int j = 0; j < 4; ++j)
                tile[mt * 16 + (lane >> 4) * 4 + j][wid * 48 + nt * 16 + row] =
                    acc[mt][nt][j];
    __syncthreads();

    for (int idx = tid; idx < 64 * C_; idx += 256) {
        int bl = idx / C_;
        int c  = idx - bl * C_;
        float y = tile[bl][I_ * C_ + c];      // j = 16, xe = 1
        const float* xrow = xe + (size_t)(b0 + bl) * NX;
#pragma unroll
        for (int j = 0; j < I_; ++j) y += xrow[j] * tile[bl][j * C_ + c];
        atomicAdd(&out[Y_OFF + (size_t)(b0 + bl) * C_ + c], y);
    }
}

extern "C" void kernel_launch(void* const* d_in, const int* in_sizes, int n_in,
                              void* d_out, int out_size, void* d_ws, size_t ws_size,
                              hipStream_t stream) {
    const float* x       = (const float*)d_in[0];
    const float* centers = (const float*)d_in[1];
    const float* widths  = (const float*)d_in[2];
    const float* cons    = (const float*)d_in[3];
    const int*   ridx    = (const int*)d_in[4];
    float* out = (float*)d_out;

    uint32_t* packed = (uint32_t*)((char*)d_ws + PK_OFF);
    uint16_t* wt     = (uint16_t*)((char*)d_ws + WT_OFF);
    uint16_t* nfb    = (uint16_t*)((char*)d_ws + WT_OFF + NPAD * R_ * 2);

    pack_kernel<<<dim3(R_ / 256), dim3(256), 0, stream>>>(ridx, packed, out);
    fuzz_wt_kernel<<<dim3(B_ + 64), dim3(256), 0, stream>>>(
        x, centers, widths, packed, cons, out, nfb, wt);
    gemm_kernel<<<dim3(B_ / 64, KSPLIT), dim3(256), 0, stream>>>(
        nfb, wt, out + XE_OFF, out);
}

// Round 9
// 47.111 us; speedup vs baseline: 1.1657x; 1.1657x over previous
//
#include <hip/hip_runtime.h>
#include <stdint.h>

typedef short short8 __attribute__((ext_vector_type(8)));
typedef float f32x4 __attribute__((ext_vector_type(4)));

#define B_ 2048
#define I_ 16
#define M_ 4
#define R_ 4096
#define C_ 10
#define NX 17           // I+1
#define NW 170          // NX*C
#define NPAD 192        // 12 MFMA n-tiles
#define KSPLIT 32
#define KCH (R_ / KSPLIT)   // 128
#define NIT (KCH / 32)      // 4

// d_out layout: y_hat (B_*C_) | norm_fs (B_*R_) | x_ext (B_*NX)
#define Y_OFF    0
#define NORM_OFF (B_ * C_)
#define XE_OFF   (B_ * C_ + B_ * R_)

// d_ws layout (bytes)
#define PK_OFF    0                                   // packed rule idx, 16 KB
#define WT_OFF    16384                               // Wt bf16 [NPAD][R_], 1.57 MB
#define NFB_OFF   (WT_OFF + NPAD * R_ * 2)            // nf bf16 [B_][R_], 16.8 MB
#define PARTY_OFF (NFB_OFF + B_ * R_ * 2)             // y partials [KSPLIT][B_][C_]

#define MFMA16(a, b, c) __builtin_amdgcn_mfma_f32_16x16x32_bf16(a, b, c, 0, 0, 0)

__device__ __forceinline__ uint16_t f2bf(float f) {
    uint32_t u = __builtin_bit_cast(uint32_t, f);
    uint32_t r = u + 0x7fffu + ((u >> 16) & 1u);    // RNE
    return (uint16_t)(r >> 16);
}

// ---------------- prep: pack rule_idx (block 64) + transpose W (blocks 0..63)
__global__ __launch_bounds__(256) void prep_kernel(
        const int* __restrict__ rule_idx, const float* __restrict__ cons,
        uint32_t* __restrict__ packed, uint16_t* __restrict__ wt) {
    int t = threadIdx.x;
    if (blockIdx.x == 64) {               // pack: 16 x 2-bit -> uint32 per rule
        for (int r = t; r < R_; r += 256) {
            uint32_t p = 0;
#pragma unroll
            for (int i = 0; i < I_; ++i)
                p |= ((uint32_t)rule_idx[i * R_ + r] & 3u) << (2 * i);
            packed[r] = p;
        }
        return;
    }
    // transpose 64 k-rows of consequents into wt[n][k] bf16 (n padded to NPAD)
    __shared__ float lt[64][NW + 1];
    int k0 = blockIdx.x * 64;
    for (int idx = t; idx < 64 * NW; idx += 256) {
        int k = idx / NW, n = idx - k * NW;
        lt[k][n] = cons[(size_t)(k0 + k) * NW + n];
    }
    __syncthreads();
    for (int idx = t; idx < NPAD * 32; idx += 256) {
        int n = idx >> 5, kp = idx & 31;
        uint32_t v = 0;
        if (n < NW) {
            uint32_t v0 = f2bf(lt[kp * 2][n]);
            uint32_t v1 = f2bf(lt[kp * 2 + 1][n]);
            v = v0 | (v1 << 16);
        }
        *(uint32_t*)(wt + (size_t)n * R_ + k0 + kp * 2) = v;
    }
}

// ---------------- per-batch: log-space quad tables, firing, norm_fs, x_ext ---
// thread owns rule pairs r = 2t + k*512, k = 0..7  (all stores lane-contiguous)
__global__ __launch_bounds__(256) void fuzz_kernel(
        const float* __restrict__ x, const float* __restrict__ centers,
        const float* __restrict__ widths, const uint32_t* __restrict__ packed,
        float* __restrict__ out, uint16_t* __restrict__ nfb) {
    int b = blockIdx.x;
    int t = threadIdx.x;
    __shared__ float xs[I_];
    __shared__ float zl[64];        // zl[i*4+m] = -(x_i-c_im)^2/(2 w_im^2) + 1e-9
    __shared__ float tab4[4 * 256]; // quad q: sum of 4 zl terms, 8-bit combo idx
    __shared__ float wsum[4];

    if (t < I_) xs[t] = x[b * I_ + t];
    if (t < NX) out[XE_OFF + b * NX + t] = (t < I_) ? x[b * I_ + t] : 1.0f;
    __syncthreads();

    if (t < 64) {
        int i = t >> 2, m = t & 3;
        float d = xs[i] - centers[i * M_ + m];
        float w = widths[i * M_ + m];
        zl[t] = -(d * d) / (2.0f * w * w) + 1e-9f;
    }
    __syncthreads();

#pragma unroll
    for (int u = 0; u < 4; ++u) {
        int idx = t + u * 256;
        int q = idx >> 8, xq = idx & 255;
        tab4[idx] = zl[q * 16 +      (xq & 3)]
                  + zl[q * 16 +  4 + ((xq >> 2) & 3)]
                  + zl[q * 16 +  8 + ((xq >> 4) & 3)]
                  + zl[q * 16 + 12 + ((xq >> 6) & 3)];
    }
    __syncthreads();

    uint2 pk[8];
#pragma unroll
    for (int k = 0; k < 8; ++k)
        pk[k] = *(const uint2*)(packed + t * 2 + k * 512);

    float fs[16];
    float lsum = 0.f;
#pragma unroll
    for (int k = 0; k < 8; ++k) {
#pragma unroll
        for (int j = 0; j < 2; ++j) {
            uint32_t p = j ? pk[k].y : pk[k].x;
            float s = tab4[        p         & 255]
                    + tab4[256 + ((p >>  8) & 255)]
                    + tab4[512 + ((p >> 16) & 255)]
                    + tab4[768 + ((p >> 24) & 255)];
            float f = __expf(s);
            fs[k * 2 + j] = f;
            lsum += f;
        }
    }
#pragma unroll
    for (int off = 32; off > 0; off >>= 1) lsum += __shfl_down(lsum, off);
    if ((t & 63) == 0) wsum[t >> 6] = lsum;
    __syncthreads();
    float inv = 1.0f / (wsum[0] + wsum[1] + wsum[2] + wsum[3] + 1e-9f);

    float* orow = out + NORM_OFF + (size_t)b * R_ + t * 2;
    uint16_t* nrow = nfb + (size_t)b * R_ + t * 2;
#pragma unroll
    for (int k = 0; k < 8; ++k) {
        float n0 = fs[k * 2] * inv;
        float n1 = fs[k * 2 + 1] * inv;
        *(float2*)(orow + k * 512) = make_float2(n0, n1);
        uint32_t pkd = (uint32_t)f2bf(n0) | ((uint32_t)f2bf(n1) << 16);
        *(uint32_t*)(nrow + k * 512) = pkd;
    }
}

// ---------------- MFMA GEMM + fused x_ext contraction -----------------------
__global__ __launch_bounds__(256, 3) void gemm_kernel(
        const uint16_t* __restrict__ nfb,   // [B_][R_] bf16
        const uint16_t* __restrict__ wt,    // [NPAD][R_] bf16 (= W^T padded)
        const float* __restrict__ xe,       // [B_][NX]
        float* __restrict__ party) {        // [KSPLIT][B_][C_]
    int bt  = blockIdx.x;           // 0..31
    int ks  = blockIdx.y;           // 0..KSPLIT-1
    int tid = threadIdx.x;
    int wid = tid >> 6;
    int lane = tid & 63;
    int b0 = bt * 64;
    int k0 = ks * KCH;
    int row = lane & 15;
    int kf  = (lane >> 4) * 8;

    f32x4 acc[4][3];
#pragma unroll
    for (int mt = 0; mt < 4; ++mt)
#pragma unroll
        for (int nt = 0; nt < 3; ++nt) acc[mt][nt] = (f32x4){0.f, 0.f, 0.f, 0.f};

    const uint16_t* Ab = nfb + (size_t)(b0 + row) * R_ + k0 + kf;
    const uint16_t* Bb = wt  + (size_t)(wid * 48 + row) * R_ + k0 + kf;

    short8 a[2][4], w[2][3];
#define LOADS(buf, kk)                                                   \
    do {                                                                 \
        a[buf][0] = *(const short8*)(Ab + (kk));                         \
        a[buf][1] = *(const short8*)(Ab + (size_t)16 * R_ + (kk));       \
        a[buf][2] = *(const short8*)(Ab + (size_t)32 * R_ + (kk));       \
        a[buf][3] = *(const short8*)(Ab + (size_t)48 * R_ + (kk));       \
        w[buf][0] = *(const short8*)(Bb + (kk));                         \
        w[buf][1] = *(const short8*)(Bb + (size_t)16 * R_ + (kk));       \
        w[buf][2] = *(const short8*)(Bb + (size_t)32 * R_ + (kk));       \
    } while (0)

    LOADS(0, 0);
#pragma unroll
    for (int it = 0; it < NIT; ++it) {
        int cur = it & 1;
        if (it + 1 < NIT) LOADS(cur ^ 1, (it + 1) * 32);
#pragma unroll
        for (int nt = 0; nt < 3; ++nt)
#pragma unroll
            for (int mt = 0; mt < 4; ++mt)
                acc[mt][nt] = MFMA16(a[cur][mt], w[cur][nt], acc[mt][nt]);
    }
#undef LOADS

    // C/D layout: col = lane&15, row = (lane>>4)*4 + j
    __shared__ float tile[64][NPAD];
#pragma unroll
    for (int mt = 0; mt < 4; ++mt)
#pragma unroll
        for (int nt = 0; nt < 3; ++nt)
#pragma unroll
            for (int j = 0; j < 4; ++j)
                tile[mt * 16 + (lane >> 4) * 4 + j][wid * 48 + nt * 16 + row] =
                    acc[mt][nt][j];
    __syncthreads();

    for (int idx = tid; idx < 64 * C_; idx += 256) {
        int bl = idx / C_;
        int c  = idx - bl * C_;
        float y = tile[bl][I_ * C_ + c];      // j = 16, xe = 1
        const float* xrow = xe + (size_t)(b0 + bl) * NX;
#pragma unroll
        for (int j = 0; j < I_; ++j) y += xrow[j] * tile[bl][j * C_ + c];
        party[((size_t)ks * B_ + b0 + bl) * C_ + c] = y;
    }
}

// ---------------- reduce K-split y partials ----------------------------------
__global__ __launch_bounds__(256) void finalize_kernel(
        const float* __restrict__ party, float* __restrict__ out) {
    int idx = blockIdx.x * 256 + threadIdx.x;
    if (idx < B_ * C_) {
        float s = 0.f;
#pragma unroll
        for (int ks = 0; ks < KSPLIT; ++ks) s += party[(size_t)ks * B_ * C_ + idx];
        out[Y_OFF + idx] = s;
    }
}

extern "C" void kernel_launch(void* const* d_in, const int* in_sizes, int n_in,
                              void* d_out, int out_size, void* d_ws, size_t ws_size,
                              hipStream_t stream) {
    const float* x       = (const float*)d_in[0];
    const float* centers = (const float*)d_in[1];
    const float* widths  = (const float*)d_in[2];
    const float* cons    = (const float*)d_in[3];
    const int*   ridx    = (const int*)d_in[4];
    float* out = (float*)d_out;

    uint32_t* packed = (uint32_t*)((char*)d_ws + PK_OFF);
    uint16_t* wt     = (uint16_t*)((char*)d_ws + WT_OFF);
    uint16_t* nfb    = (uint16_t*)((char*)d_ws + NFB_OFF);
    float*    party  = (float*)((char*)d_ws + PARTY_OFF);

    prep_kernel<<<dim3(65), dim3(256), 0, stream>>>(ridx, cons, packed, wt);
    fuzz_kernel<<<dim3(B_), dim3(256), 0, stream>>>(x, centers, widths, packed, out, nfb);
    gemm_kernel<<<dim3(B_ / 64, KSPLIT), dim3(256), 0, stream>>>(
        nfb, wt, out + XE_OFF, party);
    finalize_kernel<<<dim3((B_ * C_ + 255) / 256), dim3(256), 0, stream>>>(party, out);
}